// Round 8
// baseline (179.447 us; speedup 1.0000x reference)
//
#include <hip/hip_runtime.h>

// 9x9 box filter (r=4), reflect padding, 24 planes of 2048x2048 f32.
// R8 = R7 with the fold-in RACE fixed. Blocks in one dispatch have no
// ordering guarantee, so main blocks must NOT write the 8 boundary columns
// that the edge blocks own: lane c0==0 (half 0) and c0==W-4 (half 1) skip
// their stores (per-lane predicate, computed once). Writes are disjoint ->
// order-independent. Keeps: 4 cols/thread dense bursts, branchless ring
// rows, RH=64 (1.125x halo), XCD band swizzle, single dispatch.
// SROA rule (R5): never vector-pointer-pun local arrays; float4 temps only.

constexpr int H   = 2048;
constexpr int W   = 2048;
constexpr int R   = 4;             // radius (reference uses r=4)
constexpr int RH  = 64;            // output rows per block (72 input rows)
constexpr int TPB = 256;
constexpr int CPT = 4;             // cols per thread
constexpr int BCOLS = TPB * CPT;   // 1024 cols per block (2 halves per row)

typedef float f32x4 __attribute__((ext_vector_type(4)));

__device__ __forceinline__ int reflect_row(int r) {
  r = (r < 0) ? -r : r;
  return (r >= H) ? (2 * H - 2 - r) : r;
}

template <int P, bool STORE>
__device__ __forceinline__ void bf_step(
    int s, int r0, int off, int c0, bool doStore,
    const float* __restrict__ px, float* __restrict__ po,
    float (&hbuf)[9][CPT], float (&vsum)[CPT]) {
  const int lr = reflect_row(r0 - R + s);
  const float* __restrict__ rowp = px + (size_t)lr * W;

  // 12 floats covering 9-windows of 4 outputs: rowp[off .. off+11]
  const float4 A = *(const float4*)(rowp + off);      // v0..v3
  const float4 B = *(const float4*)(rowp + off + 4);  // v4..v7
  const float4 C = *(const float4*)(rowp + off + 8);  // v8..v11

  float h0 = ((A.x + A.y) + (A.z + A.w)) +
             ((B.x + B.y) + (B.z + B.w)) + C.x;
  float h1 = h0 + C.y - A.x;
  float h2 = h1 + C.z - A.y;
  float h3 = h2 + C.w - A.z;

  vsum[0] += h0 - hbuf[P][0]; hbuf[P][0] = h0;
  vsum[1] += h1 - hbuf[P][1]; hbuf[P][1] = h1;
  vsum[2] += h2 - hbuf[P][2]; hbuf[P][2] = h2;
  vsum[3] += h3 - hbuf[P][3]; hbuf[P][3] = h3;

  if (STORE) {
    if (doStore) {                       // skip the 2 edge-owner lanes only
      const float inv81 = 1.0f / 81.0f;
      float* o = po + (size_t)(r0 + s - 2 * R) * W + c0;
      f32x4 ov = {vsum[0] * inv81, vsum[1] * inv81,
                  vsum[2] * inv81, vsum[3] * inv81};
      __builtin_nontemporal_store(ov, (f32x4*)o);
    }
  }
}

__global__ __launch_bounds__(TPB, 5) void BoxFilter_kernel(
    const float* __restrict__ x, float* __restrict__ out, int nMain) {
  const int t   = threadIdx.x;
  const int bid = blockIdx.x;

  if (bid >= nMain) {
    // ---- edge path: exact recompute of cols 0..3 and W-4..W-1 per row ----
    const int idx   = (bid - nMain) * TPB + t;   // 0 .. planes*H-1
    const int plane = idx >> 11;
    const int r     = idx & (H - 1);
    const float* __restrict__ px = x   + (size_t)plane * H * W;
    float*       __restrict__ po = out + (size_t)plane * H * W;

    float accL[4] = {0.f, 0.f, 0.f, 0.f};
    float accR[4] = {0.f, 0.f, 0.f, 0.f};
#pragma unroll
    for (int dr = -R; dr <= R; ++dr) {
      const int rr = reflect_row(r + dr);
      const float* __restrict__ rowp = px + (size_t)rr * W;
      float l[9], m[9];
#pragma unroll
      for (int i = 0; i < 9; ++i) l[i] = rowp[i];          // cols 0..8
#pragma unroll
      for (int i = 0; i < 9; ++i) m[i] = rowp[W - 9 + i];  // cols W-9..W-1
#pragma unroll
      for (int c = 0; c < 4; ++c) {
#pragma unroll
        for (int k = -R; k <= R; ++k) {
          int j = c + k; j = (j < 0) ? -j : j;             // left col reflect
          accL[c] += l[j];
          int rc = (W - 4 + c) + k;
          rc = (rc >= W) ? (2 * W - 2 - rc) : rc;          // right col reflect
          accR[c] += m[rc - (W - 9)];
        }
      }
    }
    const float inv81 = 1.0f / 81.0f;
    float* oL = po + (size_t)r * W;
    float* oR = po + (size_t)r * W + (W - 4);
    f32x4 vL = {accL[0] * inv81, accL[1] * inv81,
                accL[2] * inv81, accL[3] * inv81};
    f32x4 vR = {accR[0] * inv81, accR[1] * inv81,
                accR[2] * inv81, accR[3] * inv81};
    *(f32x4*)oL = vL;
    *(f32x4*)oR = vR;
    return;
  }

  // ---- main path ----
  // XCD-band swizzle: bid%8 -> XCD; each XCD owns a contiguous band of
  // logical ids; logical order is chunk-fastest so vertically adjacent
  // blocks (sharing 8 halo rows) are on the same XCD's L2.
  const int lid   = (bid & 7) * (nMain >> 3) + (bid >> 3);
  const int plane = lid >> 6;          // 64 logical blocks per plane
  const int rem   = lid & 63;
  const int half  = rem >> 5;          // column half (0/1), slow
  const int chunk = rem & 31;          // row chunk, fast -> vertical locality
  const int r0    = chunk * RH;
  const int cb    = half * BCOLS;
  const float* __restrict__ px = x   + (size_t)plane * H * W;
  float*       __restrict__ po = out + (size_t)plane * H * W;

  const int c0 = cb + t * CPT;         // first output col (16B aligned)
  int off = c0 - R;                    // clamped load base (16B aligned)
  off = off < 0 ? 0 : off;
  off = off > W - 12 ? W - 12 : off;   // 2036, still 16B aligned
  // Edge-owner lanes (c0==0 and c0==W-4) computed garbage from the clamp;
  // their output columns belong to the edge blocks. Disjoint writes.
  const bool doStore = (c0 != 0) && (c0 != W - CPT);

  float hbuf[9][CPT];
  float vsum[CPT];
#pragma unroll
  for (int j = 0; j < CPT; ++j) vsum[j] = 0.0f;
#pragma unroll
  for (int p = 0; p < 9; ++p)
#pragma unroll
    for (int j = 0; j < CPT; ++j) hbuf[p][j] = 0.0f;

  // warmup: s = 0..7 (phases 0..7), no store
  bf_step<0, false>(0, r0, off, c0, doStore, px, po, hbuf, vsum);
  bf_step<1, false>(1, r0, off, c0, doStore, px, po, hbuf, vsum);
  bf_step<2, false>(2, r0, off, c0, doStore, px, po, hbuf, vsum);
  bf_step<3, false>(3, r0, off, c0, doStore, px, po, hbuf, vsum);
  bf_step<4, false>(4, r0, off, c0, doStore, px, po, hbuf, vsum);
  bf_step<5, false>(5, r0, off, c0, doStore, px, po, hbuf, vsum);
  bf_step<6, false>(6, r0, off, c0, doStore, px, po, hbuf, vsum);
  bf_step<7, false>(7, r0, off, c0, doStore, px, po, hbuf, vsum);
  // s = 8 (phase 8): first output row
  bf_step<8, true>(8, r0, off, c0, doStore, px, po, hbuf, vsum);

  // steady: s = 9..71, seven groups of 9 (phases 0..8), no tail
#pragma unroll 1
  for (int s0 = 9; s0 <= 63; s0 += 9) {
    bf_step<0, true>(s0 + 0, r0, off, c0, doStore, px, po, hbuf, vsum);
    bf_step<1, true>(s0 + 1, r0, off, c0, doStore, px, po, hbuf, vsum);
    bf_step<2, true>(s0 + 2, r0, off, c0, doStore, px, po, hbuf, vsum);
    bf_step<3, true>(s0 + 3, r0, off, c0, doStore, px, po, hbuf, vsum);
    bf_step<4, true>(s0 + 4, r0, off, c0, doStore, px, po, hbuf, vsum);
    bf_step<5, true>(s0 + 5, r0, off, c0, doStore, px, po, hbuf, vsum);
    bf_step<6, true>(s0 + 6, r0, off, c0, doStore, px, po, hbuf, vsum);
    bf_step<7, true>(s0 + 7, r0, off, c0, doStore, px, po, hbuf, vsum);
    bf_step<8, true>(s0 + 8, r0, off, c0, doStore, px, po, hbuf, vsum);
  }
}

extern "C" void kernel_launch(void* const* d_in, const int* in_sizes, int n_in,
                              void* d_out, int out_size, void* d_ws, size_t ws_size,
                              hipStream_t stream) {
  const float* x   = (const float*)d_in[0];
  float*       out = (float*)d_out;
  const int planes = out_size / (H * W);              // 8*3 = 24
  const int nMain  = planes * (H / RH) * 2;           // 24*32*2 = 1536
  const int nEdge  = planes * H / TPB;                // 192
  dim3 grid(nMain + nEdge);
  dim3 block(TPB);
  hipLaunchKernelGGL(BoxFilter_kernel, grid, block, 0, stream, x, out, nMain);
}

// Round 9
// 171.454 us; speedup vs baseline: 1.0466x; 1.0466x over previous
//
#include <hip/hip_runtime.h>

// 9x9 box filter (r=4), reflect padding, 24 planes of 2048x2048 f32.
// R9: explicit 3-deep software-pipelined loads. Diagnosis from R8: VGPR=40
// -> compiler kept hbuf in AGPRs and only ~1 row-load in flight per wave ->
// latency-serialized at ~3.3 TB/s. Fix: 3 static register slots (slot =
// s%3, compile-time because groups of 9 steps align with mod 3); each step
// consumes its slot, immediately re-issues that slot's load for s+3, then
// computes. ~9 dwordx4 in flight per wave at all times.
// Kept from R6/R8: 4 cols/thread dense bursts, branchless ring rows,
// folded edge blocks with DISJOINT writes (main lanes c0==0 / c0==W-4 skip
// stores; edge blocks own those columns -- no dispatch-order assumption).
// RH back to 32 (more TLP; halo is cache-absorbed). No XCD swizzle.
// SROA rules: float4 temps only, all array indices compile-time.

constexpr int H   = 2048;
constexpr int W   = 2048;
constexpr int R   = 4;              // radius (reference uses r=4)
constexpr int RH  = 32;             // output rows per block
constexpr int TPB = 256;
constexpr int CPT = 4;              // cols per thread
constexpr int BCOLS = TPB * CPT;    // 1024 cols per block (2 halves per row)
constexpr int STEPS = RH + 2 * R;   // 40 input-row steps

typedef float f32x4 __attribute__((ext_vector_type(4)));

struct Slot { float4 A, B, C; };    // 12 floats: rowp[off .. off+11]

__device__ __forceinline__ int reflect_row(int r) {
  r = (r < 0) ? -r : r;
  return (r >= H) ? (2 * H - 2 - r) : r;
}

template <int K>
__device__ __forceinline__ void issue_load(int s, int r0, int off,
                                           const float* __restrict__ px,
                                           Slot (&sl)[3]) {
  const int lr = reflect_row(r0 - R + s);
  const float* __restrict__ rowp = px + (size_t)lr * W + off;
  sl[K].A = *(const float4*)(rowp);
  sl[K].B = *(const float4*)(rowp + 4);
  sl[K].C = *(const float4*)(rowp + 8);
}

// P = ring phase (s%9), K = pipeline slot (s%3) -- both compile-time.
// PF: issue this slot's load for step s+3 (skipped on the last 3 steps).
template <int P, int K, bool STORE, bool PF>
__device__ __forceinline__ void bf_step(
    int s, int r0, int off, int c0, bool doStore,
    const float* __restrict__ px, float* __restrict__ po,
    Slot (&sl)[3], float (&hbuf)[9][CPT], float (&vsum)[CPT]) {
  const float4 A = sl[K].A;
  const float4 B = sl[K].B;
  const float4 C = sl[K].C;

  if (PF) issue_load<K>(s + 3, r0, off, px, sl);   // prefetch 3 steps ahead

  float h0 = ((A.x + A.y) + (A.z + A.w)) +
             ((B.x + B.y) + (B.z + B.w)) + C.x;
  float h1 = h0 + C.y - A.x;
  float h2 = h1 + C.z - A.y;
  float h3 = h2 + C.w - A.z;

  vsum[0] += h0 - hbuf[P][0]; hbuf[P][0] = h0;
  vsum[1] += h1 - hbuf[P][1]; hbuf[P][1] = h1;
  vsum[2] += h2 - hbuf[P][2]; hbuf[P][2] = h2;
  vsum[3] += h3 - hbuf[P][3]; hbuf[P][3] = h3;

  if (STORE) {
    if (doStore) {
      const float inv81 = 1.0f / 81.0f;
      float* o = po + (size_t)(r0 + s - 2 * R) * W + c0;
      f32x4 ov = {vsum[0] * inv81, vsum[1] * inv81,
                  vsum[2] * inv81, vsum[3] * inv81};
      __builtin_nontemporal_store(ov, (f32x4*)o);
    }
  }
}

__global__ __launch_bounds__(TPB, 4) void BoxFilter_kernel(
    const float* __restrict__ x, float* __restrict__ out, int nMain) {
  const int t   = threadIdx.x;
  const int bid = blockIdx.x;

  if (bid >= nMain) {
    // ---- edge path: exact recompute of cols 0..3 and W-4..W-1 per row ----
    const int idx   = (bid - nMain) * TPB + t;   // 0 .. planes*H-1
    const int plane = idx >> 11;
    const int r     = idx & (H - 1);
    const float* __restrict__ px = x   + (size_t)plane * H * W;
    float*       __restrict__ po = out + (size_t)plane * H * W;

    float accL[4] = {0.f, 0.f, 0.f, 0.f};
    float accR[4] = {0.f, 0.f, 0.f, 0.f};
#pragma unroll
    for (int dr = -R; dr <= R; ++dr) {
      const int rr = reflect_row(r + dr);
      const float* __restrict__ rowp = px + (size_t)rr * W;
      float l[9], m[9];
#pragma unroll
      for (int i = 0; i < 9; ++i) l[i] = rowp[i];          // cols 0..8
#pragma unroll
      for (int i = 0; i < 9; ++i) m[i] = rowp[W - 9 + i];  // cols W-9..W-1
#pragma unroll
      for (int c = 0; c < 4; ++c) {
#pragma unroll
        for (int k = -R; k <= R; ++k) {
          int j = c + k; j = (j < 0) ? -j : j;             // left col reflect
          accL[c] += l[j];
          int rc = (W - 4 + c) + k;
          rc = (rc >= W) ? (2 * W - 2 - rc) : rc;          // right col reflect
          accR[c] += m[rc - (W - 9)];
        }
      }
    }
    const float inv81 = 1.0f / 81.0f;
    float* oL = po + (size_t)r * W;
    float* oR = po + (size_t)r * W + (W - 4);
    f32x4 vL = {accL[0] * inv81, accL[1] * inv81,
                accL[2] * inv81, accL[3] * inv81};
    f32x4 vR = {accR[0] * inv81, accR[1] * inv81,
                accR[2] * inv81, accR[3] * inv81};
    *(f32x4*)oL = vL;
    *(f32x4*)oR = vR;
    return;
  }

  // ---- main path (natural block order; no swizzle) ----
  const int plane = bid >> 7;          // 64 chunks * 2 halves per plane
  const int rem   = bid & 127;
  const int chunk = rem >> 1;
  const int half  = rem & 1;
  const int r0    = chunk * RH;
  const int cb    = half * BCOLS;
  const float* __restrict__ px = x   + (size_t)plane * H * W;
  float*       __restrict__ po = out + (size_t)plane * H * W;

  const int c0 = cb + t * CPT;         // first output col (16B aligned)
  int off = c0 - R;                    // clamped load base (16B aligned)
  off = off < 0 ? 0 : off;
  off = off > W - 12 ? W - 12 : off;   // 2036, still 16B aligned
  const bool doStore = (c0 != 0) && (c0 != W - CPT);  // edge blocks own those

  float hbuf[9][CPT];
  float vsum[CPT];
#pragma unroll
  for (int j = 0; j < CPT; ++j) vsum[j] = 0.0f;
#pragma unroll
  for (int p = 0; p < 9; ++p)
#pragma unroll
    for (int j = 0; j < CPT; ++j) hbuf[p][j] = 0.0f;

  Slot sl[3];
  issue_load<0>(0, r0, off, px, sl);
  issue_load<1>(1, r0, off, px, sl);
  issue_load<2>(2, r0, off, px, sl);

  // warmup: s = 0..7 (phases 0..7, slots s%3), no store
  bf_step<0, 0, false, true>(0, r0, off, c0, doStore, px, po, sl, hbuf, vsum);
  bf_step<1, 1, false, true>(1, r0, off, c0, doStore, px, po, sl, hbuf, vsum);
  bf_step<2, 2, false, true>(2, r0, off, c0, doStore, px, po, sl, hbuf, vsum);
  bf_step<3, 0, false, true>(3, r0, off, c0, doStore, px, po, sl, hbuf, vsum);
  bf_step<4, 1, false, true>(4, r0, off, c0, doStore, px, po, sl, hbuf, vsum);
  bf_step<5, 2, false, true>(5, r0, off, c0, doStore, px, po, sl, hbuf, vsum);
  bf_step<6, 0, false, true>(6, r0, off, c0, doStore, px, po, sl, hbuf, vsum);
  bf_step<7, 1, false, true>(7, r0, off, c0, doStore, px, po, sl, hbuf, vsum);
  // s = 8 (phase 8, slot 2): first output row
  bf_step<8, 2, true, true>(8, r0, off, c0, doStore, px, po, sl, hbuf, vsum);

  // steady: s = 9..35, three groups of 9 (s0 % 9 == 0 and s0 % 3 == 0,
  // so phase = p, slot = p % 3 -- all compile-time)
#pragma unroll 1
  for (int s0 = 9; s0 <= 27; s0 += 9) {
    bf_step<0, 0, true, true>(s0 + 0, r0, off, c0, doStore, px, po, sl, hbuf, vsum);
    bf_step<1, 1, true, true>(s0 + 1, r0, off, c0, doStore, px, po, sl, hbuf, vsum);
    bf_step<2, 2, true, true>(s0 + 2, r0, off, c0, doStore, px, po, sl, hbuf, vsum);
    bf_step<3, 0, true, true>(s0 + 3, r0, off, c0, doStore, px, po, sl, hbuf, vsum);
    bf_step<4, 1, true, true>(s0 + 4, r0, off, c0, doStore, px, po, sl, hbuf, vsum);
    bf_step<5, 2, true, true>(s0 + 5, r0, off, c0, doStore, px, po, sl, hbuf, vsum);
    bf_step<6, 0, true, true>(s0 + 6, r0, off, c0, doStore, px, po, sl, hbuf, vsum);
    bf_step<7, 1, true, true>(s0 + 7, r0, off, c0, doStore, px, po, sl, hbuf, vsum);
    bf_step<8, 2, true, true>(s0 + 8, r0, off, c0, doStore, px, po, sl, hbuf, vsum);
  }
  // tail: s = 36..39 (phases 0..3, slots 0,1,2,0); 36 still prefetches 39
  bf_step<0, 0, true, true >(36, r0, off, c0, doStore, px, po, sl, hbuf, vsum);
  bf_step<1, 1, true, false>(37, r0, off, c0, doStore, px, po, sl, hbuf, vsum);
  bf_step<2, 2, true, false>(38, r0, off, c0, doStore, px, po, sl, hbuf, vsum);
  bf_step<3, 0, true, false>(39, r0, off, c0, doStore, px, po, sl, hbuf, vsum);
}

extern "C" void kernel_launch(void* const* d_in, const int* in_sizes, int n_in,
                              void* d_out, int out_size, void* d_ws, size_t ws_size,
                              hipStream_t stream) {
  const float* x   = (const float*)d_in[0];
  float*       out = (float*)d_out;
  const int planes = out_size / (H * W);              // 8*3 = 24
  const int nMain  = planes * (H / RH) * 2;           // 24*64*2 = 3072
  const int nEdge  = planes * H / TPB;                // 192
  dim3 grid(nMain + nEdge);
  dim3 block(TPB);
  hipLaunchKernelGGL(BoxFilter_kernel, grid, block, 0, stream, x, out, nMain);
}